// Round 8
// baseline (126.679 us; speedup 1.0000x reference)
//
#include <hip/hip_runtime.h>
#include <math.h>

#define PI_F 3.14159265358979323846f
#define FLAG_MAGIC 0x9E3779B9u

typedef int v2i __attribute__((ext_vector_type(2)));

__device__ __forceinline__ float rcpf(float x) { return __builtin_amdgcn_rcpf(x); }
__device__ __forceinline__ void fswap(float2& p, float2& q) { float2 t = p; p = q; q = t; }

// ---------------------------------------------------------------------------
// QCNN: one wave per sample, 256-amp state in registers (4 float2/lane).
// qubit0 -> reg bit1, qubit1 -> reg bit0, qubit q in 2..7 -> lane bit (q-2).
// (UNCHANGED from the passing r4/r6 kernel.)
// ---------------------------------------------------------------------------

template<int Q>
__device__ __forceinline__ float exq(float v) {
    if constexpr (Q == 2)        // lane^1: quad_perm [1,0,3,2]
        return __int_as_float(__builtin_amdgcn_update_dpp(0, __float_as_int(v), 0xB1, 0xF, 0xF, true));
    else if constexpr (Q == 3)   // lane^2: quad_perm [2,3,0,1]
        return __int_as_float(__builtin_amdgcn_update_dpp(0, __float_as_int(v), 0x4E, 0xF, 0xF, true));
    else if constexpr (Q == 4)   // lane^4
        return __int_as_float(__builtin_amdgcn_ds_swizzle(__float_as_int(v), 0x101F));
    else if constexpr (Q == 5)   // lane^8
        return __int_as_float(__builtin_amdgcn_ds_swizzle(__float_as_int(v), 0x201F));
    else if constexpr (Q == 6)   // lane^16
        return __int_as_float(__builtin_amdgcn_ds_swizzle(__float_as_int(v), 0x401F));
    else {                       // lane^32: permlane32_swap, pure VALU
        v2i r = __builtin_amdgcn_permlane32_swap(__float_as_int(v), __float_as_int(v), false, false);
        return __int_as_float((threadIdx.x & 32) ? r[0] : r[1]);
    }
}

template<int Q>
__device__ __forceinline__ void rzg(float2 a[4], float th, int lane) {
    float c = __cosf(0.5f * th), s = __sinf(0.5f * th);
    if constexpr (Q >= 2) {
        float se = ((lane >> (Q - 2)) & 1) ? s : -s;
        #pragma unroll
        for (int r = 0; r < 4; ++r) {
            float nx = c * a[r].x - se * a[r].y;
            float ny = c * a[r].y + se * a[r].x;
            a[r] = make_float2(nx, ny);
        }
    } else {
        #pragma unroll
        for (int r = 0; r < 4; ++r) {
            int bit = (Q == 0) ? (r >> 1) : (r & 1);
            float se = bit ? s : -s;
            float nx = c * a[r].x - se * a[r].y;
            float ny = c * a[r].y + se * a[r].x;
            a[r] = make_float2(nx, ny);
        }
    }
}

template<int Q>
__device__ __forceinline__ void ryg(float2 a[4], float th, int lane) {
    float c = __cosf(0.5f * th), s = __sinf(0.5f * th);
    if constexpr (Q >= 2) {
        float se = ((lane >> (Q - 2)) & 1) ? s : -s;
        #pragma unroll
        for (int r = 0; r < 4; ++r) {
            float ox = exq<Q>(a[r].x), oy = exq<Q>(a[r].y);
            a[r] = make_float2(c * a[r].x + se * ox, c * a[r].y + se * oy);
        }
    } else if constexpr (Q == 0) {
        #pragma unroll
        for (int r = 0; r < 2; ++r) {
            float2 lo = a[r], hi = a[r + 2];
            a[r]     = make_float2(c * lo.x - s * hi.x, c * lo.y - s * hi.y);
            a[r + 2] = make_float2(s * lo.x + c * hi.x, s * lo.y + c * hi.y);
        }
    } else {
        #pragma unroll
        for (int r = 0; r < 4; r += 2) {
            float2 lo = a[r], hi = a[r + 1];
            a[r]     = make_float2(c * lo.x - s * hi.x, c * lo.y - s * hi.y);
            a[r + 1] = make_float2(s * lo.x + c * hi.x, s * lo.y + c * hi.y);
        }
    }
}

template<int C, int T>
__device__ __forceinline__ void cxg(float2 a[4], int lane) {
    if constexpr (C >= 2) {
        bool cb = (lane >> (C - 2)) & 1;
        #pragma unroll
        for (int r = 0; r < 4; ++r) {
            float ox = exq<T>(a[r].x), oy = exq<T>(a[r].y);
            a[r].x = cb ? ox : a[r].x;
            a[r].y = cb ? oy : a[r].y;
        }
    } else if constexpr (C == 0 && T == 1) {
        fswap(a[2], a[3]);
    } else {
        fswap(a[1], a[3]);
    }
}

template<int Q>
__device__ __forceinline__ void featg(float2 a[4], float xq, int lane) {
    float phi = 2.0f * xq;
    float e1x = __cosf(phi), e1y = __sinf(phi);
    float e2x = e1x * e1x - e1y * e1y;
    float e2y = 2.0f * e1x * e1y;
    float2 u00 = make_float2(0.5f * (1.0f + e1x),  0.5f * e1y);
    float2 u01 = make_float2(0.5f * (1.0f - e1x), -0.5f * e1y);
    float2 u10 = make_float2(0.5f * (e1x - e2x), 0.5f * (e1y - e2y));
    float2 u11 = make_float2(0.5f * (e1x + e2x), 0.5f * (e1y + e2y));
    if constexpr (Q >= 2) {
        bool bset = (lane >> (Q - 2)) & 1;
        float csx = bset ? u11.x : u00.x, csy = bset ? u11.y : u00.y;
        float cox = bset ? u10.x : u01.x, coy = bset ? u10.y : u01.y;
        #pragma unroll
        for (int r = 0; r < 4; ++r) {
            float ox = exq<Q>(a[r].x), oy = exq<Q>(a[r].y);
            float nx = csx * a[r].x - csy * a[r].y + cox * ox - coy * oy;
            float ny = csx * a[r].y + csy * a[r].x + cox * oy + coy * ox;
            a[r] = make_float2(nx, ny);
        }
    } else {
        float2 l, h;
        #define APPL(LO, HI)                                                        \
            l = a[LO]; h = a[HI];                                                   \
            a[LO] = make_float2(u00.x*l.x - u00.y*l.y + u01.x*h.x - u01.y*h.y,      \
                                u00.x*l.y + u00.y*l.x + u01.x*h.y + u01.y*h.x);     \
            a[HI] = make_float2(u10.x*l.x - u10.y*l.y + u11.x*h.x - u11.y*h.y,      \
                                u10.x*l.y + u10.y*l.x + u11.x*h.y + u11.y*h.x);
        if constexpr (Q == 0) { APPL(0, 2) APPL(1, 3) }
        else                  { APPL(0, 1) APPL(2, 3) }
        #undef APPL
    }
}

template<int Q1, int Q2>
__device__ __forceinline__ void convg(float2 a[4], const float* __restrict__ p, int lane) {
    rzg<Q2>(a, -0.5f * PI_F, lane);
    cxg<Q2, Q1>(a, lane);
    rzg<Q1>(a, p[0], lane);
    ryg<Q2>(a, p[1], lane);
    cxg<Q1, Q2>(a, lane);
    ryg<Q2>(a, p[2], lane);
    cxg<Q2, Q1>(a, lane);
    rzg<Q1>(a, 0.5f * PI_F, lane);
}

template<int Q1, int Q2>
__device__ __forceinline__ void poolg(float2 a[4], const float* __restrict__ p, int lane) {
    rzg<Q2>(a, -0.5f * PI_F, lane);
    cxg<Q2, Q1>(a, lane);
    rzg<Q1>(a, p[0], lane);
    ryg<Q2>(a, p[1], lane);
    cxg<Q1, Q2>(a, lane);
    ryg<Q2>(a, p[2], lane);
}

template<int CTRL>
__device__ __forceinline__ float bq(float v) {   // quad_perm broadcast
    return __int_as_float(__builtin_amdgcn_update_dpp(0, __float_as_int(v), CTRL, 0xF, 0xF, true));
}

__device__ __forceinline__ float pick4(bool b0, bool b1, float a0, float a1, float a2, float a3) {
    float t01 = b0 ? a1 : a0;
    float t23 = b0 ? a3 : a2;
    return b1 ? t23 : t01;
}

// Pade [5/4] tanh: x(x^4+105x^2+945)/(15x^4+420x^2+945); err <= 4.5e-8, |x|<=1
__device__ __forceinline__ float tanh54(float x) {
    float u = x * x;
    float N = fmaf(u, u + 105.0f, 945.0f);
    float D = fmaf(u, fmaf(15.0f, u, 420.0f), 945.0f);
    return x * N * rcpf(D);
}

// Pade [7/6] tanh: x(x^6+378x^4+17325x^2+135135)/(28x^6+3150x^4+62370x^2+135135)
// err ~2e-8 at |x|<=2.1 (two CF levels beyond [5/4]'s 1.5e-5 at 2.1)
__device__ __forceinline__ float tanh76(float x) {
    float u = x * x;
    float N = fmaf(u, fmaf(u, u + 378.0f, 17325.0f), 135135.0f);
    float D = fmaf(u, fmaf(u, fmaf(28.0f, u, 3150.0f), 62370.0f), 135135.0f);
    return x * N * rcpf(D);
}

// ---------------------------------------------------------------------------
// Fused kernel, PIPELINED handoff. One dispatch.
//   blocks 0..511 : QCNN producers; flag n = blockIdx*4 + wave, TIMESTEP-MAJOR
//                   (n = t*16 + b) so early blocks produce early timesteps.
//   block 512     : wave 0 = QLSTM consumer (r4 layout: lane=(b,q), 16
//                   batches lockstep, 4-wide in-lane ILP).
// Handoff: flg[n] = (float_bits(qcnn_n) << 32) | (MAGIC ^ epoch); epoch at
// flg+2048, bumped by consumer each launch (replay/poison-safe; r1/r4/r6/r7).
//
// MODEL (r4=46/r6=46/r7=63 triangulation): LSTM floor = dependent trans-chain
// latency (~100 cyc/dep-use on a lone wave); r4 chain has 5 trans-class ops
// (cos, exp, rcp, exp, rcp) => ~750 cyc/step. r7 removed spill pressure and
// got SLOWER (added swizzle+DPP hops to chain, lost ILP) - spills exonerated.
// THIS ROUND: cut chain trans 5 -> 3 via division-form rational nonlinearities
// (Pade [5/4] for gates, args |x|<=1; Pade [7/6] for tanh(c), |c|<=2.1 bound
// from F,I,G ranges). Per-step added error <=2e-8..2e-7 vs exp-form; with the
// measured ~4e4 amplification (1e-7/step -> 0.0039) expect absmax ~0.004-0.008
// vs threshold 0.0199. NOTE: [5/4] on tanh(c) would be 1.5e-5/step -> FAIL;
// [7/6] is required there. DPP all unconditional (r2/r3 lesson).
// ---------------------------------------------------------------------------

__device__ __forceinline__ void stage_chunk(int m, int lane, unsigned key,
                                            unsigned long long* __restrict__ flg,
                                            float* qsh) {
    int idx = m * 64 + lane;             // idx = t*16 + b
    unsigned long long v = __hip_atomic_load(&flg[idx], __ATOMIC_RELAXED, __HIP_MEMORY_SCOPE_AGENT);
    while ((unsigned)v != key) {
        __builtin_amdgcn_s_sleep(1);     // gentle spin: producers share the CU
        v = __hip_atomic_load(&flg[idx], __ATOMIC_RELAXED, __HIP_MEMORY_SCOPE_AGENT);
    }
    qsh[(idx & 15) * 132 + (idx >> 4)] = __uint_as_float((unsigned)(v >> 32));
}

__global__ __launch_bounds__(256, 1) void fused_kernel(
    const float* __restrict__ x,  const float* __restrict__ w,
    const float* __restrict__ thf, const float* __restrict__ thi,
    const float* __restrict__ thg, const float* __restrict__ tho,
    const float* __restrict__ Wf, const float* __restrict__ bf,
    const float* __restrict__ Wi, const float* __restrict__ bi,
    const float* __restrict__ Wg, const float* __restrict__ bg,
    const float* __restrict__ Wo, const float* __restrict__ bo,
    const float* __restrict__ Wh, const float* __restrict__ bh,
    float* __restrict__ out, unsigned long long* __restrict__ flg) {
    __shared__ __align__(16) float qsh[16 * 132];   // padded rows: conflict-free
    int lane = threadIdx.x & 63;
    int wave = threadIdx.x >> 6;
    unsigned* epoch = (unsigned*)(flg + 2048);

    if (blockIdx.x != 512) {
        // ---------------- QCNN producer (UNCHANGED) ----------------
        unsigned key = FLAG_MAGIC ^ __hip_atomic_load(epoch, __ATOMIC_RELAXED, __HIP_MEMORY_SCOPE_AGENT);
        int n = blockIdx.x * 4 + wave;   // flag index, timestep-major
        int bb = n & 15, tt = n >> 4;    // batch, timestep
        int sidx = bb * 128 + tt;        // x/out layout index (batch-major)
        float2 a[4];
        a[0] = make_float2(lane == 0 ? 1.0f : 0.0f, 0.0f);
        a[1] = make_float2(0.0f, 0.0f);
        a[2] = make_float2(0.0f, 0.0f);
        a[3] = make_float2(0.0f, 0.0f);

        const float* xr = x + sidx * 8;
        featg<0>(a, xr[0], lane);
        featg<1>(a, xr[1], lane);
        featg<2>(a, xr[2], lane);
        featg<3>(a, xr[3], lane);
        featg<4>(a, xr[4], lane);
        featg<5>(a, xr[5], lane);
        featg<6>(a, xr[6], lane);
        featg<7>(a, xr[7], lane);

        convg<0,1>(a, w + 0,  lane);
        convg<2,3>(a, w + 3,  lane);
        convg<4,5>(a, w + 6,  lane);
        convg<6,7>(a, w + 9,  lane);
        poolg<0,1>(a, w + 12, lane);
        poolg<2,3>(a, w + 15, lane);
        poolg<4,5>(a, w + 18, lane);
        poolg<6,7>(a, w + 21, lane);
        convg<0,1>(a, w + 24, lane);
        convg<2,3>(a, w + 27, lane);
        poolg<0,1>(a, w + 30, lane);
        poolg<2,3>(a, w + 33, lane);
        convg<0,1>(a, w + 36, lane);
        poolg<0,1>(a, w + 39, lane);

        float ssum = 0.f;
        #pragma unroll
        for (int r = 0; r < 4; ++r)
            ssum += a[r].x * a[r].x + a[r].y * a[r].y;
        ssum = (lane & 32) ? -ssum : ssum;
        ssum += exq<2>(ssum);
        ssum += exq<3>(ssum);
        ssum += exq<4>(ssum);
        ssum += exq<5>(ssum);
        ssum += exq<6>(ssum);
        {
            v2i rr = __builtin_amdgcn_permlane32_swap(__float_as_int(ssum), __float_as_int(ssum), false, false);
            ssum = __int_as_float((threadIdx.x & 32) ? rr[0] : rr[1]) +
                   __int_as_float((threadIdx.x & 32) ? rr[1] : rr[0]);
        }
        if (lane == 0) {
            out[sidx] = ssum;
            unsigned long long pk = ((unsigned long long)__float_as_uint(ssum) << 32)
                                  | (unsigned long long)key;
            __hip_atomic_store(&flg[n], pk, __ATOMIC_RELAXED, __HIP_MEMORY_SCOPE_AGENT);
        }
        return;
    }

    // ---------------- QLSTM consumer (block 512, wave 0 only) ----------------
    if (wave != 0) return;
    unsigned key = FLAG_MAGIC ^ __hip_atomic_load(epoch, __ATOMIC_RELAXED, __HIP_MEMORY_SCOPE_AGENT);

    int b = lane >> 2, q = lane & 3;
    bool qb0 = q & 1, qb1 = q & 2;
    const float* Wp = (q == 0) ? Wf : (q == 1) ? Wi : (q == 2) ? Wg : Wo;
    const float* bp = (q == 0) ? bf : (q == 1) ? bi : (q == 2) ? bg : bo;
    const float* tp = (q == 0) ? thf : (q == 1) ? thi : (q == 2) ? thg : tho;

    // loop-invariant loads hoisted before the spin (latency hides under wait)
    float W0_ = Wp[0],  W1_ = Wp[1],  W2_ = Wp[2],  W3_ = Wp[3],  W4_ = Wp[4];
    float W5_ = Wp[5],  W6_ = Wp[6],  W7_ = Wp[7],  W8_ = Wp[8],  W9_ = Wp[9];
    float W10_ = Wp[10], W11_ = Wp[11], W12_ = Wp[12], W13_ = Wp[13], W14_ = Wp[14];
    float W15_ = Wp[15], W16_ = Wp[16], W17_ = Wp[17], W18_ = Wp[18], W19_ = Wp[19];
    float av0 = bp[0] + tp[0], av1 = bp[1] + tp[1];
    float av2 = bp[2] + tp[2], av3 = bp[3] + tp[3];
    float wh0 = Wh[0], wh1 = Wh[1], wh2 = Wh[2], wh3 = Wh[3], bh0 = bh[0];

    stage_chunk(0, lane, key, flg, qsh);      // timesteps 0..3
    __builtin_amdgcn_wave_barrier();

    // gate nonlinearity as n = A + B * tanh54(S * r):
    //   sigmoid(r) = 0.5 + 0.5*tanh(r/2)  (S=0.5, arg <= 0.5)
    //   tanh(r)    for q==2               (S=1,   arg <= 1)
    float S2 = (q == 2) ? 1.0f : 0.5f;
    float A2 = (q == 2) ? 0.0f : 0.5f;
    float B2 = (q == 2) ? 1.0f : 0.5f;

    float c = 0.f;
    float h0 = 0.f, h1 = 0.f, h2 = 0.f, h3 = 0.f;
    const float* qrow = &qsh[b * 132];

    for (int j = 0; j < 32; ++j) {
        if (j < 31) stage_chunk(j + 1, lane, key, flg, qsh);  // lookahead
        __builtin_amdgcn_wave_barrier();
        float4 xq4 = *(const float4*)&qrow[4 * j];   // 16B-aligned ds_read_b128
        #pragma unroll
        for (int k = 0; k < 4; ++k) {
            float xv = (k == 0) ? xq4.x : (k == 1) ? xq4.y : (k == 2) ? xq4.z : xq4.w;
            float vA = av0 + W0_*xv  + W1_*h0  + W2_*h1  + W3_*h2  + W4_*h3;
            float vB = av1 + W5_*xv  + W6_*h0  + W7_*h1  + W8_*h2  + W9_*h3;
            float vC = av2 + W10_*xv + W11_*h0 + W12_*h1 + W13_*h2 + W14_*h3;
            float vD = av3 + W15_*xv + W16_*h0 + W17_*h1 + W18_*h2 + W19_*h3;
            float cA = __cosf(vA), cB = __cosf(vB), cC = __cosf(vC), cD = __cosf(vD);
            float r1 = cA * cB, r2 = r1 * cC, r3 = r2 * cD, r0 = cB * (cC * cD);
            // rational nonlinearity: polys + ONE rcp per value (4 rcps issue in
            // parallel -> one dep latency in chain, vs exp+rcp = two)
            float n0 = fmaf(B2, tanh54(S2 * r0), A2);
            float n1 = fmaf(B2, tanh54(S2 * r1), A2);
            float n2 = fmaf(B2, tanh54(S2 * r2), A2);
            float n3 = fmaf(B2, tanh54(S2 * r3), A2);
            // quad transpose: 16 bq DPP (unconditional) + 12 cndmask (r4-verbatim)
            float F0 = bq<0x00>(n0), F1 = bq<0x00>(n1), F2 = bq<0x00>(n2), F3 = bq<0x00>(n3);
            float I0 = bq<0x55>(n0), I1 = bq<0x55>(n1), I2 = bq<0x55>(n2), I3 = bq<0x55>(n3);
            float G0 = bq<0xAA>(n0), G1 = bq<0xAA>(n1), G2 = bq<0xAA>(n2), G3 = bq<0xAA>(n3);
            float O0 = bq<0xFF>(n0), O1 = bq<0xFF>(n1), O2 = bq<0xFF>(n2), O3 = bq<0xFF>(n3);
            float F = pick4(qb0, qb1, F0, F1, F2, F3);
            float I = pick4(qb0, qb1, I0, I1, I2, I3);
            float G = pick4(qb0, qb1, G0, G1, G2, G3);
            float O = pick4(qb0, qb1, O0, O1, O2, O3);
            c = F * c + I * G;
            float tau = tanh76(c);               // |c| <= 2.07 (F,I,G bounds)
            float hq = O * tau;
            h0 = bq<0x00>(hq);
            h1 = bq<0x55>(hq);
            h2 = bq<0xAA>(hq);
            h3 = bq<0xFF>(hq);
        }
    }

    if (q == 0)
        out[2048 + b] = bh0 + wh0*h0 + wh1*h1 + wh2*h2 + wh3*h3;

    if (lane == 0)
        __hip_atomic_fetch_add(epoch, 1u, __ATOMIC_RELAXED, __HIP_MEMORY_SCOPE_AGENT);
}

extern "C" void kernel_launch(void* const* d_in, const int* in_sizes, int n_in,
                              void* d_out, int out_size, void* d_ws, size_t ws_size,
                              hipStream_t stream) {
    fused_kernel<<<513, 256, 0, stream>>>(
        (const float*)d_in[0],  (const float*)d_in[1],
        (const float*)d_in[2],  (const float*)d_in[3],
        (const float*)d_in[4],  (const float*)d_in[5],
        (const float*)d_in[6],  (const float*)d_in[7],
        (const float*)d_in[8],  (const float*)d_in[9],
        (const float*)d_in[10], (const float*)d_in[11],
        (const float*)d_in[12], (const float*)d_in[13],
        (const float*)d_in[14], (const float*)d_in[15],
        (float*)d_out, (unsigned long long*)d_ws);
}

// Round 9
// 111.654 us; speedup vs baseline: 1.1346x; 1.1346x over previous
//
#include <hip/hip_runtime.h>
#include <math.h>

#define PI_F 3.14159265358979323846f
#define FLAG_MAGIC 0x9E3779B9u

typedef int v2i __attribute__((ext_vector_type(2)));
typedef float v2f __attribute__((ext_vector_type(2)));

__device__ __forceinline__ float rcpf(float x) { return __builtin_amdgcn_rcpf(x); }
__device__ __forceinline__ void fswap(float2& p, float2& q) { float2 t = p; p = q; q = t; }
__device__ __forceinline__ v2f pkfma(v2f a, v2f b, v2f c) { return __builtin_elementwise_fma(a, b, c); }

// ---------------------------------------------------------------------------
// QCNN: one wave per sample, 256-amp state in registers (4 float2/lane).
// qubit0 -> reg bit1, qubit1 -> reg bit0, qubit q in 2..7 -> lane bit (q-2).
// (UNCHANGED from the passing r4/r6/r8 kernel.)
// ---------------------------------------------------------------------------

template<int Q>
__device__ __forceinline__ float exq(float v) {
    if constexpr (Q == 2)        // lane^1: quad_perm [1,0,3,2]
        return __int_as_float(__builtin_amdgcn_update_dpp(0, __float_as_int(v), 0xB1, 0xF, 0xF, true));
    else if constexpr (Q == 3)   // lane^2: quad_perm [2,3,0,1]
        return __int_as_float(__builtin_amdgcn_update_dpp(0, __float_as_int(v), 0x4E, 0xF, 0xF, true));
    else if constexpr (Q == 4)   // lane^4
        return __int_as_float(__builtin_amdgcn_ds_swizzle(__float_as_int(v), 0x101F));
    else if constexpr (Q == 5)   // lane^8
        return __int_as_float(__builtin_amdgcn_ds_swizzle(__float_as_int(v), 0x201F));
    else if constexpr (Q == 6)   // lane^16
        return __int_as_float(__builtin_amdgcn_ds_swizzle(__float_as_int(v), 0x401F));
    else {                       // lane^32: permlane32_swap, pure VALU
        v2i r = __builtin_amdgcn_permlane32_swap(__float_as_int(v), __float_as_int(v), false, false);
        return __int_as_float((threadIdx.x & 32) ? r[0] : r[1]);
    }
}

template<int Q>
__device__ __forceinline__ void rzg(float2 a[4], float th, int lane) {
    float c = __cosf(0.5f * th), s = __sinf(0.5f * th);
    if constexpr (Q >= 2) {
        float se = ((lane >> (Q - 2)) & 1) ? s : -s;
        #pragma unroll
        for (int r = 0; r < 4; ++r) {
            float nx = c * a[r].x - se * a[r].y;
            float ny = c * a[r].y + se * a[r].x;
            a[r] = make_float2(nx, ny);
        }
    } else {
        #pragma unroll
        for (int r = 0; r < 4; ++r) {
            int bit = (Q == 0) ? (r >> 1) : (r & 1);
            float se = bit ? s : -s;
            float nx = c * a[r].x - se * a[r].y;
            float ny = c * a[r].y + se * a[r].x;
            a[r] = make_float2(nx, ny);
        }
    }
}

template<int Q>
__device__ __forceinline__ void ryg(float2 a[4], float th, int lane) {
    float c = __cosf(0.5f * th), s = __sinf(0.5f * th);
    if constexpr (Q >= 2) {
        float se = ((lane >> (Q - 2)) & 1) ? s : -s;
        #pragma unroll
        for (int r = 0; r < 4; ++r) {
            float ox = exq<Q>(a[r].x), oy = exq<Q>(a[r].y);
            a[r] = make_float2(c * a[r].x + se * ox, c * a[r].y + se * oy);
        }
    } else if constexpr (Q == 0) {
        #pragma unroll
        for (int r = 0; r < 2; ++r) {
            float2 lo = a[r], hi = a[r + 2];
            a[r]     = make_float2(c * lo.x - s * hi.x, c * lo.y - s * hi.y);
            a[r + 2] = make_float2(s * lo.x + c * hi.x, s * lo.y + c * hi.y);
        }
    } else {
        #pragma unroll
        for (int r = 0; r < 4; r += 2) {
            float2 lo = a[r], hi = a[r + 1];
            a[r]     = make_float2(c * lo.x - s * hi.x, c * lo.y - s * hi.y);
            a[r + 1] = make_float2(s * lo.x + c * hi.x, s * lo.y + c * hi.y);
        }
    }
}

template<int C, int T>
__device__ __forceinline__ void cxg(float2 a[4], int lane) {
    if constexpr (C >= 2) {
        bool cb = (lane >> (C - 2)) & 1;
        #pragma unroll
        for (int r = 0; r < 4; ++r) {
            float ox = exq<T>(a[r].x), oy = exq<T>(a[r].y);
            a[r].x = cb ? ox : a[r].x;
            a[r].y = cb ? oy : a[r].y;
        }
    } else if constexpr (C == 0 && T == 1) {
        fswap(a[2], a[3]);
    } else {
        fswap(a[1], a[3]);
    }
}

template<int Q>
__device__ __forceinline__ void featg(float2 a[4], float xq, int lane) {
    float phi = 2.0f * xq;
    float e1x = __cosf(phi), e1y = __sinf(phi);
    float e2x = e1x * e1x - e1y * e1y;
    float e2y = 2.0f * e1x * e1y;
    float2 u00 = make_float2(0.5f * (1.0f + e1x),  0.5f * e1y);
    float2 u01 = make_float2(0.5f * (1.0f - e1x), -0.5f * e1y);
    float2 u10 = make_float2(0.5f * (e1x - e2x), 0.5f * (e1y - e2y));
    float2 u11 = make_float2(0.5f * (e1x + e2x), 0.5f * (e1y + e2y));
    if constexpr (Q >= 2) {
        bool bset = (lane >> (Q - 2)) & 1;
        float csx = bset ? u11.x : u00.x, csy = bset ? u11.y : u00.y;
        float cox = bset ? u10.x : u01.x, coy = bset ? u10.y : u01.y;
        #pragma unroll
        for (int r = 0; r < 4; ++r) {
            float ox = exq<Q>(a[r].x), oy = exq<Q>(a[r].y);
            float nx = csx * a[r].x - csy * a[r].y + cox * ox - coy * oy;
            float ny = csx * a[r].y + csy * a[r].x + cox * oy + coy * ox;
            a[r] = make_float2(nx, ny);
        }
    } else {
        float2 l, h;
        #define APPL(LO, HI)                                                        \
            l = a[LO]; h = a[HI];                                                   \
            a[LO] = make_float2(u00.x*l.x - u00.y*l.y + u01.x*h.x - u01.y*h.y,      \
                                u00.x*l.y + u00.y*l.x + u01.x*h.y + u01.y*h.x);     \
            a[HI] = make_float2(u10.x*l.x - u10.y*l.y + u11.x*h.x - u11.y*h.y,      \
                                u10.x*l.y + u10.y*l.x + u11.x*h.y + u11.y*h.x);
        if constexpr (Q == 0) { APPL(0, 2) APPL(1, 3) }
        else                  { APPL(0, 1) APPL(2, 3) }
        #undef APPL
    }
}

template<int Q1, int Q2>
__device__ __forceinline__ void convg(float2 a[4], const float* __restrict__ p, int lane) {
    rzg<Q2>(a, -0.5f * PI_F, lane);
    cxg<Q2, Q1>(a, lane);
    rzg<Q1>(a, p[0], lane);
    ryg<Q2>(a, p[1], lane);
    cxg<Q1, Q2>(a, lane);
    ryg<Q2>(a, p[2], lane);
    cxg<Q2, Q1>(a, lane);
    rzg<Q1>(a, 0.5f * PI_F, lane);
}

template<int Q1, int Q2>
__device__ __forceinline__ void poolg(float2 a[4], const float* __restrict__ p, int lane) {
    rzg<Q2>(a, -0.5f * PI_F, lane);
    cxg<Q2, Q1>(a, lane);
    rzg<Q1>(a, p[0], lane);
    ryg<Q2>(a, p[1], lane);
    cxg<Q1, Q2>(a, lane);
    ryg<Q2>(a, p[2], lane);
}

template<int CTRL>
__device__ __forceinline__ float bq(float v) {   // quad_perm broadcast
    return __int_as_float(__builtin_amdgcn_update_dpp(0, __float_as_int(v), CTRL, 0xF, 0xF, true));
}

__device__ __forceinline__ float dpp1(float v) { // quad xor1
    return __int_as_float(__builtin_amdgcn_update_dpp(0, __float_as_int(v), 0xB1, 0xF, 0xF, true));
}
__device__ __forceinline__ float dpp2(float v) { // quad xor2
    return __int_as_float(__builtin_amdgcn_update_dpp(0, __float_as_int(v), 0x4E, 0xF, 0xF, true));
}

// ---------------------------------------------------------------------------
// Fused kernel, PIPELINED handoff + PREFETCH-SPLIT staging. One dispatch.
//   blocks 0..511 : QCNN producers; flag n = blockIdx*4 + wave, TIMESTEP-MAJOR
//                   (n = t*16 + b) so early blocks produce early timesteps.
//   block 512     : wave 0 = QLSTM consumer (r4 layout: lane=(b,q)).
// Handoff: flg[n] = (float_bits(qcnn_n) << 32) | (MAGIC ^ epoch); epoch at
// flg+2048, bumped by consumer each launch (replay/poison-safe; r1..r8).
//
// MODEL (r4=46 / r6-pin=46 / r7-serial=63 / r8-poly=49 triangulation): the
// LSTM is ISSUE+DEP-bound on total VALU op count for a lone wave (~4-5
// cyc/op), plus ~200-300 cyc/step of EXPOSED cross-XCD atomic staging
// latency (blocking spin at each chunk top). Not trans-latency (r8 null),
// not spills (r6 null, r7 worse).
// THIS ROUND: (1) prefetch-split staging -- issue chunk j+1's flag load
// before computing chunk j, spin-check+LDS-write after (hides ~900 cyc);
// (2) packed h-dots via v_pk_fma (16 fma -> 8 pk), x-part hoisted to chunk
// top (association identical to r4's contracted fma chain -> bit-identical);
// (3) 8-DPP+8-cndmask quad transpose (was 16 DPP+12 cnd) with every DPP
// result bound to a named variable UNCONDITIONALLY before any select
// (r2/r3 lesson: DPP must never lower under divergent exec).
// Nonlinearities stay r4's exp form. ~90 -> ~61 ops/step.
// ---------------------------------------------------------------------------

__global__ __launch_bounds__(256, 1) void fused_kernel(
    const float* __restrict__ x,  const float* __restrict__ w,
    const float* __restrict__ thf, const float* __restrict__ thi,
    const float* __restrict__ thg, const float* __restrict__ tho,
    const float* __restrict__ Wf, const float* __restrict__ bf,
    const float* __restrict__ Wi, const float* __restrict__ bi,
    const float* __restrict__ Wg, const float* __restrict__ bg,
    const float* __restrict__ Wo, const float* __restrict__ bo,
    const float* __restrict__ Wh, const float* __restrict__ bh,
    float* __restrict__ out, unsigned long long* __restrict__ flg) {
    __shared__ __align__(16) float qsh[16 * 132];   // padded rows: conflict-free
    int lane = threadIdx.x & 63;
    int wave = threadIdx.x >> 6;
    unsigned* epoch = (unsigned*)(flg + 2048);

    if (blockIdx.x != 512) {
        // ---------------- QCNN producer (UNCHANGED) ----------------
        unsigned key = FLAG_MAGIC ^ __hip_atomic_load(epoch, __ATOMIC_RELAXED, __HIP_MEMORY_SCOPE_AGENT);
        int n = blockIdx.x * 4 + wave;   // flag index, timestep-major
        int bb = n & 15, tt = n >> 4;    // batch, timestep
        int sidx = bb * 128 + tt;        // x/out layout index (batch-major)
        float2 a[4];
        a[0] = make_float2(lane == 0 ? 1.0f : 0.0f, 0.0f);
        a[1] = make_float2(0.0f, 0.0f);
        a[2] = make_float2(0.0f, 0.0f);
        a[3] = make_float2(0.0f, 0.0f);

        const float* xr = x + sidx * 8;
        featg<0>(a, xr[0], lane);
        featg<1>(a, xr[1], lane);
        featg<2>(a, xr[2], lane);
        featg<3>(a, xr[3], lane);
        featg<4>(a, xr[4], lane);
        featg<5>(a, xr[5], lane);
        featg<6>(a, xr[6], lane);
        featg<7>(a, xr[7], lane);

        convg<0,1>(a, w + 0,  lane);
        convg<2,3>(a, w + 3,  lane);
        convg<4,5>(a, w + 6,  lane);
        convg<6,7>(a, w + 9,  lane);
        poolg<0,1>(a, w + 12, lane);
        poolg<2,3>(a, w + 15, lane);
        poolg<4,5>(a, w + 18, lane);
        poolg<6,7>(a, w + 21, lane);
        convg<0,1>(a, w + 24, lane);
        convg<2,3>(a, w + 27, lane);
        poolg<0,1>(a, w + 30, lane);
        poolg<2,3>(a, w + 33, lane);
        convg<0,1>(a, w + 36, lane);
        poolg<0,1>(a, w + 39, lane);

        float ssum = 0.f;
        #pragma unroll
        for (int r = 0; r < 4; ++r)
            ssum += a[r].x * a[r].x + a[r].y * a[r].y;
        ssum = (lane & 32) ? -ssum : ssum;
        ssum += exq<2>(ssum);
        ssum += exq<3>(ssum);
        ssum += exq<4>(ssum);
        ssum += exq<5>(ssum);
        ssum += exq<6>(ssum);
        {
            v2i rr = __builtin_amdgcn_permlane32_swap(__float_as_int(ssum), __float_as_int(ssum), false, false);
            ssum = __int_as_float((threadIdx.x & 32) ? rr[0] : rr[1]) +
                   __int_as_float((threadIdx.x & 32) ? rr[1] : rr[0]);
        }
        if (lane == 0) {
            out[sidx] = ssum;
            unsigned long long pk = ((unsigned long long)__float_as_uint(ssum) << 32)
                                  | (unsigned long long)key;
            __hip_atomic_store(&flg[n], pk, __ATOMIC_RELAXED, __HIP_MEMORY_SCOPE_AGENT);
        }
        return;
    }

    // ---------------- QLSTM consumer (block 512, wave 0 only) ----------------
    if (wave != 0) return;
    unsigned key = FLAG_MAGIC ^ __hip_atomic_load(epoch, __ATOMIC_RELAXED, __HIP_MEMORY_SCOPE_AGENT);

    int b = lane >> 2, q = lane & 3;
    bool qb0 = q & 1, qb1 = q & 2;
    const float* Wp = (q == 0) ? Wf : (q == 1) ? Wi : (q == 2) ? Wg : Wo;
    const float* bp = (q == 0) ? bf : (q == 1) ? bi : (q == 2) ? bg : bo;
    const float* tp = (q == 0) ? thf : (q == 1) ? thi : (q == 2) ? thg : tho;

    // loop-invariant loads (latency hides under the chunk-0 spin below)
    float W0_ = Wp[0],  W1_ = Wp[1],  W2_ = Wp[2],  W3_ = Wp[3],  W4_ = Wp[4];
    float W5_ = Wp[5],  W6_ = Wp[6],  W7_ = Wp[7],  W8_ = Wp[8],  W9_ = Wp[9];
    float W10_ = Wp[10], W11_ = Wp[11], W12_ = Wp[12], W13_ = Wp[13], W14_ = Wp[14];
    float W15_ = Wp[15], W16_ = Wp[16], W17_ = Wp[17], W18_ = Wp[18], W19_ = Wp[19];
    float av0 = bp[0] + tp[0], av1 = bp[1] + tp[1];
    float av2 = bp[2] + tp[2], av3 = bp[3] + tp[3];
    float wh0 = Wh[0], wh1 = Wh[1], wh2 = Wh[2], wh3 = Wh[3], bh0 = bh[0];

    // packed invariant pairs: (row A, row B) and (row C, row D)
    v2f wxAB = {W0_, W5_},  wxCD = {W10_, W15_};
    v2f avAB = {av0, av1},  avCD = {av2, av3};
    v2f w1AB = {W1_, W6_},  w2AB = {W2_, W7_},  w3AB = {W3_, W8_},  w4AB = {W4_, W9_};
    v2f w1CD = {W11_, W16_}, w2CD = {W12_, W17_}, w3CD = {W13_, W18_}, w4CD = {W14_, W19_};

    // blocking stage of chunk 0 (timesteps 0..3)
    {
        int idx = lane;
        unsigned long long v = __hip_atomic_load(&flg[idx], __ATOMIC_RELAXED, __HIP_MEMORY_SCOPE_AGENT);
        while ((unsigned)v != key) {
            __builtin_amdgcn_s_sleep(1);
            v = __hip_atomic_load(&flg[idx], __ATOMIC_RELAXED, __HIP_MEMORY_SCOPE_AGENT);
        }
        qsh[(idx & 15) * 132 + (idx >> 4)] = __uint_as_float((unsigned)(v >> 32));
    }
    // issue prefetch for chunk 1 (latency hides under chunk-0 compute)
    int pidx = 64 + lane;
    unsigned long long pv = __hip_atomic_load(&flg[pidx], __ATOMIC_RELAXED, __HIP_MEMORY_SCOPE_AGENT);
    __builtin_amdgcn_wave_barrier();

    // gate-q nonlinearity constants (verbatim r4: tanh for q==2, else sigmoid)
    float nA = (q == 2) ? 1.0f : 0.0f;
    float nB = (q == 2) ? -2.0f : 1.0f;
    float nK = (q == 2) ? 2.0f : -1.0f;

    float c = 0.f;
    float h0 = 0.f, h1 = 0.f, h2 = 0.f, h3 = 0.f;
    const float* qrow = &qsh[b * 132];

    for (int j = 0; j < 32; ++j) {
        float4 xq4 = *(const float4*)&qrow[4 * j];   // 16B-aligned ds_read_b128
        // x-part for all 4 steps, off the h-chain (ax = fma(W0, xv, av): same
        // association as r4's contracted "av + W0*xv" head of the dot chain)
        v2f axAB[4], axCD[4];
        {
            v2f xv0 = {xq4.x, xq4.x}, xv1 = {xq4.y, xq4.y};
            v2f xv2 = {xq4.z, xq4.z}, xv3 = {xq4.w, xq4.w};
            axAB[0] = pkfma(wxAB, xv0, avAB); axCD[0] = pkfma(wxCD, xv0, avCD);
            axAB[1] = pkfma(wxAB, xv1, avAB); axCD[1] = pkfma(wxCD, xv1, avCD);
            axAB[2] = pkfma(wxAB, xv2, avAB); axCD[2] = pkfma(wxCD, xv2, avCD);
            axAB[3] = pkfma(wxAB, xv3, avAB); axCD[3] = pkfma(wxCD, xv3, avCD);
        }
        #pragma unroll
        for (int k = 0; k < 4; ++k) {
            // packed h-dot: per-component fma sequence identical to r4's
            // contracted chain (left-assoc, h0..h3 order)
            v2f hv0 = {h0, h0}, hv1 = {h1, h1}, hv2 = {h2, h2}, hv3 = {h3, h3};
            v2f vAB = pkfma(w1AB, hv0, axAB[k]);
            v2f vCD = pkfma(w1CD, hv0, axCD[k]);
            vAB = pkfma(w2AB, hv1, vAB);  vCD = pkfma(w2CD, hv1, vCD);
            vAB = pkfma(w3AB, hv2, vAB);  vCD = pkfma(w3CD, hv2, vCD);
            vAB = pkfma(w4AB, hv3, vAB);  vCD = pkfma(w4CD, hv3, vCD);
            float cA = __cosf(vAB.x), cB = __cosf(vAB.y);
            float cC = __cosf(vCD.x), cD = __cosf(vCD.y);
            float r1 = cA * cB, r2 = r1 * cC, r3 = r2 * cD, r0 = cB * (cC * cD);
            // unified nonlinearity (verbatim r4: exp-based)
            float E0 = __expf(nK * r0), E1 = __expf(nK * r1);
            float E2 = __expf(nK * r2), E3 = __expf(nK * r3);
            float n0 = nA + nB * rcpf(E0 + 1.0f);
            float n1 = nA + nB * rcpf(E1 + 1.0f);
            float n2 = nA + nB * rcpf(E2 + 1.0f);
            float n3 = nA + nB * rcpf(E3 + 1.0f);
            // 8-DPP quad transpose: every DPP bound to a named var, executed
            // unconditionally; selects afterwards (algebra verified all lanes)
            float d0 = dpp1(n0), d1 = dpp1(n1), d2 = dpp1(n2), d3 = dpp1(n3);
            float A0 = qb0 ? d1 : n0;
            float A1 = qb0 ? n1 : d0;
            float A2 = qb0 ? d3 : n2;
            float A3 = qb0 ? n3 : d2;
            float e0 = dpp2(A0), e1 = dpp2(A1), e2 = dpp2(A2), e3 = dpp2(A3);
            float F = qb1 ? e2 : A0;
            float I = qb1 ? e3 : A1;
            float G = qb1 ? A2 : e0;
            float O = qb1 ? A3 : e1;
            c = F * c + I * G;
            float Ec = __expf(2.0f * c);
            float tau = 1.0f - 2.0f * rcpf(Ec + 1.0f);
            float hq = O * tau;
            h0 = bq<0x00>(hq);
            h1 = bq<0x55>(hq);
            h2 = bq<0xAA>(hq);
            h3 = bq<0xFF>(hq);
        }
        // finalize prefetched chunk j+1 (latency already hidden), issue j+2
        if (j < 31) {
            while ((unsigned)pv != key) {
                __builtin_amdgcn_s_sleep(1);
                pv = __hip_atomic_load(&flg[pidx], __ATOMIC_RELAXED, __HIP_MEMORY_SCOPE_AGENT);
            }
            qsh[(pidx & 15) * 132 + (pidx >> 4)] = __uint_as_float((unsigned)(pv >> 32));
            pidx += 64;
            if (j < 30)
                pv = __hip_atomic_load(&flg[pidx], __ATOMIC_RELAXED, __HIP_MEMORY_SCOPE_AGENT);
        }
        __builtin_amdgcn_wave_barrier();     // single wave: LDS program-ordered
    }

    if (q == 0)
        out[2048 + b] = bh0 + wh0*h0 + wh1*h1 + wh2*h2 + wh3*h3;

    if (lane == 0)
        __hip_atomic_fetch_add(epoch, 1u, __ATOMIC_RELAXED, __HIP_MEMORY_SCOPE_AGENT);
}

extern "C" void kernel_launch(void* const* d_in, const int* in_sizes, int n_in,
                              void* d_out, int out_size, void* d_ws, size_t ws_size,
                              hipStream_t stream) {
    fused_kernel<<<513, 256, 0, stream>>>(
        (const float*)d_in[0],  (const float*)d_in[1],
        (const float*)d_in[2],  (const float*)d_in[3],
        (const float*)d_in[4],  (const float*)d_in[5],
        (const float*)d_in[6],  (const float*)d_in[7],
        (const float*)d_in[8],  (const float*)d_in[9],
        (const float*)d_in[10], (const float*)d_in[11],
        (const float*)d_in[12], (const float*)d_in[13],
        (const float*)d_in[14], (const float*)d_in[15],
        (float*)d_out, (unsigned long long*)d_ws);
}